// Round 14
// baseline (100.261 us; speedup 1.0000x reference)
//
#include <hip/hip_runtime.h>

typedef _Float16 half2_t __attribute__((ext_vector_type(2)));
typedef _Float16 f16x8   __attribute__((ext_vector_type(8)));
typedef float    f32x16  __attribute__((ext_vector_type(16)));

#define TPB    256
#define NF     32
#define T_TOT  406
#define LLEN   2048
#define NPAIR  496
#define NCH    29          // chunks per batch; 29*14 = 406 exactly
#define WPB    14          // windows per chunk (7 window-pairs)
#define W2S    36          // W2 row stride (u32)
#define ZS     32          // Z row stride (u32)
#define OTS    8           // ot row stride (u32 slots)

__device__ __forceinline__ float dot2(unsigned int a, unsigned int b, float c) {
    return __builtin_amdgcn_fdot2(__builtin_bit_cast(half2_t, a),
                                  __builtin_bit_cast(half2_t, b), c, false);
}
__device__ __forceinline__ unsigned int pkrtz(float a, float b) {
    return __builtin_bit_cast(unsigned int, __builtin_amdgcn_cvt_pkrtz(a, b));
}

__global__ __launch_bounds__(TPB)
void tscorr_kernel(const float* __restrict__ x, float* __restrict__ out) {
    __shared__ union {
        unsigned int W2[2][44][W2S];     // 12672 B: f16-pair-packed X (2 parities)
        unsigned int ot[NPAIR * OTS];    // 15872 B: f16-pair out tile
    } R;
    __shared__ unsigned int Zs[WPB * 10 * ZS];   // 17920 B: normalized z windows

    const int tid = threadIdx.x;

    // XCD-pinned decode: all 29 chunks of batch b run on XCD b%8
    const int n     = blockIdx.x;
    const int xcd   = n & 7;
    const int slot  = n >> 3;            // 0..927
    const int bidx  = slot / NCH;        // 0..31
    const int chunk = slot - bidx * NCH; // 0..28
    const int b     = xcd + 8 * bidx;

    const int l0     = chunk * (WPB * 5);    // chunk*70 (even)
    const int lstart = l0 & ~3;              // 16B-aligned
    const int off    = l0 - lstart;          // 0 or 2 (even)
    const float* xb  = x + (size_t)b * NF * LLEN;

    // ---------------- stage: float4 loads -> f16 pairs, both parities ----------------
    {
        const int f  = tid >> 3;             // 0..31
        const int p4 = tid & 7;              // 0..7
        #pragma unroll
        for (int it = 0; it < 3; ++it) {
            const int grp = p4 + it * 8;     // 0..23
            if (grp < 22) {                  // rows 0..87
                const int pos = grp * 4;
                const float4 v = *(const float4*)&xb[f * LLEN + lstart + pos];
                const float v4 = (lstart + pos + 4 < LLEN)
                                     ? xb[f * LLEN + lstart + pos + 4] : 0.f;
                R.W2[0][2 * grp    ][f] = pkrtz(v.x, v.y);
                R.W2[0][2 * grp + 1][f] = pkrtz(v.z, v.w);
                R.W2[1][2 * grp    ][f] = pkrtz(v.y, v.z);
                R.W2[1][2 * grp + 1][f] = pkrtz(v.w, v4);
            }
        }
    }
    __syncthreads();

    // ------- fused stats + Z-normalize: thread = (f, t) column, regs reused -------
    {
        const unsigned int ONES = 0x3C003C00u;        // (1.0h, 1.0h)
        for (int idx = tid; idx < NF * WPB; idx += TPB) {   // 448 columns
            const int t   = idx >> 5;        // 0..13
            const int ff  = idx & 31;        // lanes span all banks
            const int par = t & 1;
            const int ms  = (off + 5 * t - par) >> 1;
            const unsigned int* p0 = &R.W2[par][ms][ff];
            unsigned int h[10];
            float S = 0.f, G = 0.f;
            #pragma unroll
            for (int q = 0; q < 10; ++q) {
                h[q] = p0[q * W2S];
                S = dot2(h[q], ONES, S);     // sum x
                G = dot2(h[q], h[q], G);     // sum x^2
            }
            const float nn = sqrtf(fmaxf(G - S * S * 0.05f, 0.f));
            const float rn = __builtin_amdgcn_rcpf(fmaxf(nn, 1e-6f));
            const float mb = -(S * 0.05f) * rn;       // -mu*rn
            unsigned int* zo = &Zs[(t * 10) * ZS + ff];
            #pragma unroll
            for (int q = 0; q < 10; ++q) {
                const half2_t hp = __builtin_bit_cast(half2_t, h[q]);
                const float z0 = fmaf((float)hp.x, rn, mb);
                const float z1 = fmaf((float)hp.y, rn, mb);
                zo[q * ZS] = pkrtz(z0, z1);
            }
        }
    }
    __syncthreads();

    // -------- main: 4 waves, wave wv does window-pairs {wv, wv+4} --------
    {
        const int wv   = tid >> 6;           // 0..3
        const int lane = tid & 63;
        const int jz   = lane & 31;          // fragment feature row
        const int hi   = lane >> 5;

        // transposed-C epilogue constants (Gram symmetric): i = lane, j = reg
        const int i   = jz;
        const int tri = i * (63 - i) / 2;
        const int pbh = tri - i - 1 + 4 * hi;    // p = pbh + jl
        const int thr = i - 4 * hi;              // write iff jl > thr

        for (int pr = wv; pr < 7; pr += 4) {     // waves 0-2: 2 pairs, wave 3: 1
            f32x16 C0, C1;
            #pragma unroll
            for (int r = 0; r < 16; ++r) { C0[r] = 0.f; C1[r] = 0.f; }

            #pragma unroll
            for (int w = 0; w < 2; ++w) {
                const int t = 2 * pr + w;
                const unsigned int* base = &Zs[(t * 10 + 4 * hi) * ZS + jz];
                union { unsigned int u[4]; f16x8 h; } u1;
                u1.u[0] = base[0];
                u1.u[1] = base[ZS];
                u1.u[2] = base[2 * ZS];
                u1.u[3] = base[3 * ZS];
                union { unsigned int u[4]; f16x8 h; } u2;
                u2.u[2] = 0u; u2.u[3] = 0u;
                if (hi == 0) {               // k=16..19 live only in low half
                    const unsigned int* b2 = &Zs[(t * 10 + 8) * ZS + jz];
                    u2.u[0] = b2[0];
                    u2.u[1] = b2[ZS];
                } else { u2.u[0] = 0u; u2.u[1] = 0u; }
                if (w == 0) {
                    C0 = __builtin_amdgcn_mfma_f32_32x32x16_f16(u1.h, u1.h, C0, 0, 0, 0);
                    C0 = __builtin_amdgcn_mfma_f32_32x32x16_f16(u2.h, u2.h, C0, 0, 0, 0);
                } else {
                    C1 = __builtin_amdgcn_mfma_f32_32x32x16_f16(u1.h, u1.h, C1, 0, 0, 0);
                    C1 = __builtin_amdgcn_mfma_f32_32x32x16_f16(u2.h, u2.h, C1, 0, 0, 0);
                }
            }

            // epilogue: C IS the correlation; 1 add + 1 cmp + pack per entry
            #pragma unroll
            for (int r = 0; r < 16; ++r) {
                const int jl = (r & 3) + 8 * (r >> 2);   // compile-time
                if (jl > thr) {
                    const int p = pbh + jl;
                    R.ot[p * OTS + (pr ^ (p & 4))] = pkrtz(C0[r], C1[r]);
                }
            }
        }
    }
    __syncthreads();

    // ------- sweep: uint4 reads, float2 stores; slot s holds pr = s ^ (p&4) -------
    float* ob = out + (size_t)b * NPAIR * T_TOT + chunk * WPB;
    for (int k = tid; k < NPAIR * 2; k += TPB) {
        const int p  = k >> 1;
        const int h  = k & 1;
        const int p4 = (p >> 2) & 1;
        const int hp = h ^ p4;               // t-half: prs 4*hp..4*hp+3
        const uint4 v = *(const uint4*)&R.ot[p * OTS + h * 4];
        float* po = &ob[(size_t)p * T_TOT + 8 * hp];
        const unsigned int u[4] = {v.x, v.y, v.z, v.w};
        #pragma unroll
        for (int e = 0; e < 4; ++e) {
            if (hp == 0 || e < 3) {          // pr=7 slot is garbage
                const half2_t hh = __builtin_bit_cast(half2_t, u[e]);
                float2 o;
                o.x = (float)hh.x;
                o.y = (float)hh.y;
                *(float2*)&po[2 * e] = o;    // 8B aligned
            }
        }
    }
}

extern "C" void kernel_launch(void* const* d_in, const int* in_sizes, int n_in,
                              void* d_out, int out_size, void* d_ws, size_t ws_size,
                              hipStream_t stream) {
    (void)in_sizes; (void)n_in; (void)out_size; (void)d_ws; (void)ws_size;
    const float* x = (const float*)d_in[0];
    float* out     = (float*)d_out;
    const int nblocks = 8 * 32 * NCH;        // 7424
    hipLaunchKernelGGL(tscorr_kernel, dim3(nblocks), dim3(TPB), 0, stream, x, out);
}

// Round 15
// 74.792 us; speedup vs baseline: 1.3405x; 1.3405x over previous
//
#include <hip/hip_runtime.h>

typedef _Float16 half2_t __attribute__((ext_vector_type(2)));
typedef _Float16 f16x8   __attribute__((ext_vector_type(8)));
typedef float    f32x16  __attribute__((ext_vector_type(16)));

#define TPB    256
#define NF     32
#define T_TOT  406
#define LLEN   2048
#define NPAIR  496
#define NCH    29          // chunks per batch; 29*14 = 406 exactly
#define WPB    14          // windows per chunk (7 window-pairs)
#define W2S    36          // W2 row stride (u32)
#define ZS     32          // Z row stride (u32)
#define OTS    7           // ot row stride (u32 slots): stride 7 coprime w/ 32 banks

__device__ __forceinline__ float dot2(unsigned int a, unsigned int b, float c) {
    return __builtin_amdgcn_fdot2(__builtin_bit_cast(half2_t, a),
                                  __builtin_bit_cast(half2_t, b), c, false);
}
__device__ __forceinline__ unsigned int pkrtz(float a, float b) {
    return __builtin_bit_cast(unsigned int, __builtin_amdgcn_cvt_pkrtz(a, b));
}

__global__ __launch_bounds__(TPB)
void tscorr_kernel(const float* __restrict__ x, float* __restrict__ out) {
    __shared__ union {
        unsigned int W2[2][44][W2S];     // 12672 B: f16-pair-packed X (2 parities)
        unsigned int ot[NPAIR * OTS];    // 13888 B: f16-pair out tile, stride 7
    } R;
    __shared__ unsigned int Zs[WPB * 10 * ZS];   // 17920 B: normalized z windows
    // total 31808 B -> 5 blocks/CU

    const int tid = threadIdx.x;

    // XCD-pinned decode: all 29 chunks of batch b run on XCD b%8
    const int n     = blockIdx.x;
    const int xcd   = n & 7;
    const int slot  = n >> 3;            // 0..927
    const int bidx  = slot / NCH;        // 0..31
    const int chunk = slot - bidx * NCH; // 0..28
    const int b     = xcd + 8 * bidx;

    const int l0     = chunk * (WPB * 5);    // chunk*70 (even)
    const int lstart = l0 & ~3;              // 16B-aligned
    const int off    = l0 - lstart;          // 0 or 2 (even)
    const float* xb  = x + (size_t)b * NF * LLEN;

    // ---------------- stage: float4 loads -> f16 pairs, both parities ----------------
    {
        const int f  = tid >> 3;             // 0..31
        const int p4 = tid & 7;              // 0..7
        #pragma unroll
        for (int it = 0; it < 3; ++it) {
            const int grp = p4 + it * 8;     // 0..23
            if (grp < 22) {                  // rows 0..87
                const int pos = grp * 4;
                const float4 v = *(const float4*)&xb[f * LLEN + lstart + pos];
                const float v4 = (lstart + pos + 4 < LLEN)
                                     ? xb[f * LLEN + lstart + pos + 4] : 0.f;
                R.W2[0][2 * grp    ][f] = pkrtz(v.x, v.y);
                R.W2[0][2 * grp + 1][f] = pkrtz(v.z, v.w);
                R.W2[1][2 * grp    ][f] = pkrtz(v.y, v.z);
                R.W2[1][2 * grp + 1][f] = pkrtz(v.w, v4);
            }
        }
    }
    __syncthreads();

    // ------- fused stats + Z-normalize: thread = (f, t) column, regs reused -------
    {
        const unsigned int ONES = 0x3C003C00u;        // (1.0h, 1.0h)
        for (int idx = tid; idx < NF * WPB; idx += TPB) {   // 448 columns
            const int t   = idx >> 5;        // 0..13
            const int ff  = idx & 31;        // lanes span all banks
            const int par = t & 1;
            const int ms  = (off + 5 * t - par) >> 1;
            const unsigned int* p0 = &R.W2[par][ms][ff];
            unsigned int h[10];
            float S = 0.f, G = 0.f;
            #pragma unroll
            for (int q = 0; q < 10; ++q) {
                h[q] = p0[q * W2S];
                S = dot2(h[q], ONES, S);     // sum x
                G = dot2(h[q], h[q], G);     // sum x^2
            }
            const float nn = sqrtf(fmaxf(G - S * S * 0.05f, 0.f));
            const float rn = __builtin_amdgcn_rcpf(fmaxf(nn, 1e-6f));
            const float mb = -(S * 0.05f) * rn;       // -mu*rn
            unsigned int* zo = &Zs[(t * 10) * ZS + ff];
            #pragma unroll
            for (int q = 0; q < 10; ++q) {
                const half2_t hp = __builtin_bit_cast(half2_t, h[q]);
                const float z0 = fmaf((float)hp.x, rn, mb);
                const float z1 = fmaf((float)hp.y, rn, mb);
                zo[q * ZS] = pkrtz(z0, z1);
            }
        }
    }
    __syncthreads();

    // -------- main: 4 waves, wave wv does window-pairs {wv, wv+4} --------
    {
        const int wv   = tid >> 6;           // 0..3
        const int lane = tid & 63;
        const int jz   = lane & 31;          // fragment feature row / C column j
        const int hi   = lane >> 5;

        for (int pr = wv; pr < 7; pr += 4) { // waves 0-2: 2 pairs, wave 3: 1
            f32x16 C0, C1;
            #pragma unroll
            for (int r = 0; r < 16; ++r) { C0[r] = 0.f; C1[r] = 0.f; }

            #pragma unroll
            for (int w = 0; w < 2; ++w) {
                const int t = 2 * pr + w;
                const unsigned int* base = &Zs[(t * 10 + 4 * hi) * ZS + jz];
                union { unsigned int u[4]; f16x8 h; } u1;
                u1.u[0] = base[0];
                u1.u[1] = base[ZS];
                u1.u[2] = base[2 * ZS];
                u1.u[3] = base[3 * ZS];
                union { unsigned int u[4]; f16x8 h; } u2;
                u2.u[2] = 0u; u2.u[3] = 0u;
                if (hi == 0) {               // k=16..19 live only in low half
                    const unsigned int* b2 = &Zs[(t * 10 + 8) * ZS + jz];
                    u2.u[0] = b2[0];
                    u2.u[1] = b2[ZS];
                } else { u2.u[0] = 0u; u2.u[1] = 0u; }
                if (w == 0) {
                    C0 = __builtin_amdgcn_mfma_f32_32x32x16_f16(u1.h, u1.h, C0, 0, 0, 0);
                    C0 = __builtin_amdgcn_mfma_f32_32x32x16_f16(u2.h, u2.h, C0, 0, 0, 0);
                } else {
                    C1 = __builtin_amdgcn_mfma_f32_32x32x16_f16(u1.h, u1.h, C1, 0, 0, 0);
                    C1 = __builtin_amdgcn_mfma_f32_32x32x16_f16(u2.h, u2.h, C1, 0, 0, 0);
                }
            }

            // epilogue: C IS the correlation. j = lane, i = reg (compile-time base);
            // p consecutive across lanes -> addr = 7p + pr, stride 7 (coprime 32):
            // conflict-free ds_write with zero swizzle math.
            #pragma unroll
            for (int r = 0; r < 16; ++r) {
                const int il = (r & 3) + 8 * (r >> 2);   // compile-time
                const int i  = il + 4 * hi;              // C row
                const int j  = jz;                       // C column
                if (j > i) {
                    const int p = i * (63 - i) / 2 + (j - i - 1);
                    R.ot[p * OTS + pr] = pkrtz(C0[r], C1[r]);
                }
            }
        }
    }
    __syncthreads();

    // ------- sweep: linear walk, conflict-free reads, float2 stores -------
    float* ob = out + (size_t)b * NPAIR * T_TOT + chunk * WPB;
    for (int k = tid; k < NPAIR * OTS; k += TPB) {
        const int p  = k / OTS;              // magic-div
        const int pr = k - p * OTS;          // 0..6
        const half2_t hh = __builtin_bit_cast(half2_t, R.ot[k]);
        float2 o;
        o.x = (float)hh.x;
        o.y = (float)hh.y;
        *(float2*)&ob[(size_t)p * T_TOT + 2 * pr] = o;   // 8B aligned
    }
}

extern "C" void kernel_launch(void* const* d_in, const int* in_sizes, int n_in,
                              void* d_out, int out_size, void* d_ws, size_t ws_size,
                              hipStream_t stream) {
    (void)in_sizes; (void)n_in; (void)out_size; (void)d_ws; (void)ws_size;
    const float* x = (const float*)d_in[0];
    float* out     = (float*)d_out;
    const int nblocks = 8 * 32 * NCH;        // 7424
    hipLaunchKernelGGL(tscorr_kernel, dim3(nblocks), dim3(TPB), 0, stream, x, out);
}

// Round 16
// 62.839 us; speedup vs baseline: 1.5955x; 1.1902x over previous
//
#include <hip/hip_runtime.h>

typedef _Float16 half2_t __attribute__((ext_vector_type(2)));
typedef _Float16 f16x8   __attribute__((ext_vector_type(8)));
typedef float    f32x16  __attribute__((ext_vector_type(16)));

#define TPB    256
#define NF     32
#define T_TOT  406
#define LLEN   2048
#define NPAIR  496
#define NCH    29          // chunks per batch; 29*14 = 406 exactly
#define WPB    14          // windows per chunk (7 window-pairs)
#define W2S    36          // W2 row stride (u32)
#define ZS     32          // Z row stride (u32)
#define OTS    8           // ot row stride (u32 slots)

__device__ __forceinline__ float dot2(unsigned int a, unsigned int b, float c) {
    return __builtin_amdgcn_fdot2(__builtin_bit_cast(half2_t, a),
                                  __builtin_bit_cast(half2_t, b), c, false);
}
__device__ __forceinline__ unsigned int pkrtz(float a, float b) {
    return __builtin_bit_cast(unsigned int, __builtin_amdgcn_cvt_pkrtz(a, b));
}

__global__ __launch_bounds__(TPB)
void tscorr_kernel(const float* __restrict__ x, float* __restrict__ out) {
    __shared__ union {
        unsigned int W2[2][44][W2S];     // 12672 B: f16-pair-packed X (2 parities)
        unsigned int ot[NPAIR * OTS];    // 15872 B: f16-pair out tile
    } R;
    __shared__ unsigned int Zs[WPB * 10 * ZS];   // 17920 B: normalized z windows

    const int tid = threadIdx.x;

    // XCD-pinned decode: all 29 chunks of batch b run on XCD b%8
    const int n     = blockIdx.x;
    const int xcd   = n & 7;
    const int slot  = n >> 3;            // 0..927
    const int bidx  = slot / NCH;        // 0..31
    const int chunk = slot - bidx * NCH; // 0..28
    const int b     = xcd + 8 * bidx;

    const int l0     = chunk * (WPB * 5);    // chunk*70 (even)
    const int lstart = l0 & ~3;              // 16B-aligned
    const int off    = l0 - lstart;          // 0 or 2 (even)
    const float* xb  = x + (size_t)b * NF * LLEN;

    // ---------------- stage: float4 loads -> f16 pairs, both parities ----------------
    {
        const int f  = tid >> 3;             // 0..31
        const int p4 = tid & 7;              // 0..7
        #pragma unroll
        for (int it = 0; it < 3; ++it) {
            const int grp = p4 + it * 8;     // 0..23
            if (grp < 22) {                  // rows 0..87
                const int pos = grp * 4;
                const float4 v = *(const float4*)&xb[f * LLEN + lstart + pos];
                const float v4 = (lstart + pos + 4 < LLEN)
                                     ? xb[f * LLEN + lstart + pos + 4] : 0.f;
                R.W2[0][2 * grp    ][f] = pkrtz(v.x, v.y);
                R.W2[0][2 * grp + 1][f] = pkrtz(v.z, v.w);
                R.W2[1][2 * grp    ][f] = pkrtz(v.y, v.z);
                R.W2[1][2 * grp + 1][f] = pkrtz(v.w, v4);
            }
        }
    }
    __syncthreads();

    // ------- fused stats + Z-normalize: thread = (f, t) column, regs reused -------
    {
        const unsigned int ONES = 0x3C003C00u;        // (1.0h, 1.0h)
        for (int idx = tid; idx < NF * WPB; idx += TPB) {   // 448 columns
            const int t   = idx >> 5;        // 0..13
            const int ff  = idx & 31;        // lanes span all banks
            const int par = t & 1;
            const int ms  = (off + 5 * t - par) >> 1;
            const unsigned int* p0 = &R.W2[par][ms][ff];
            unsigned int h[10];
            float S = 0.f, G = 0.f;
            #pragma unroll
            for (int q = 0; q < 10; ++q) {
                h[q] = p0[q * W2S];
                S = dot2(h[q], ONES, S);     // sum x
                G = dot2(h[q], h[q], G);     // sum x^2
            }
            const float nn = sqrtf(fmaxf(G - S * S * 0.05f, 0.f));
            const float rn = __builtin_amdgcn_rcpf(fmaxf(nn, 1e-6f));
            const float mb = -(S * 0.05f) * rn;       // -mu*rn
            unsigned int* zo = &Zs[(t * 10) * ZS + ff];
            #pragma unroll
            for (int q = 0; q < 10; ++q) {
                const half2_t hp = __builtin_bit_cast(half2_t, h[q]);
                const float z0 = fmaf((float)hp.x, rn, mb);
                const float z1 = fmaf((float)hp.y, rn, mb);
                zo[q * ZS] = pkrtz(z0, z1);
            }
        }
    }
    __syncthreads();

    // -------- main: wave = window-pair, MFMA Gram of normalized Z --------
    // A/B fragments identical (Gram): lane l: row/col = l&31, k = 8*(l>>5)+e.
    // K=20 = one full K=16 mfma + one mfma with only k=16..19 live (rest zeroed).
    {
        const int wv   = tid >> 6;
        const int lane = tid & 63;
        const int j    = lane & 31;          // C column
        const int hi   = lane >> 5;

        for (int pr = wv; pr < 7; pr += 4) { // waves 0-2: 2 pairs, wave 3: 1
            f32x16 C0, C1;
            #pragma unroll
            for (int r = 0; r < 16; ++r) { C0[r] = 0.f; C1[r] = 0.f; }

            #pragma unroll
            for (int w = 0; w < 2; ++w) {
                const int t = 2 * pr + w;
                const unsigned int* base = &Zs[(t * 10 + 4 * hi) * ZS + j];
                union { unsigned int u[4]; f16x8 h; } u1;
                u1.u[0] = base[0];
                u1.u[1] = base[ZS];
                u1.u[2] = base[2 * ZS];
                u1.u[3] = base[3 * ZS];
                union { unsigned int u[4]; f16x8 h; } u2;
                u2.u[2] = 0u; u2.u[3] = 0u;
                if (hi == 0) {               // k=16..19 live only in low half
                    const unsigned int* b2 = &Zs[(t * 10 + 8) * ZS + j];
                    u2.u[0] = b2[0];
                    u2.u[1] = b2[ZS];
                } else { u2.u[0] = 0u; u2.u[1] = 0u; }
                if (w == 0) {
                    C0 = __builtin_amdgcn_mfma_f32_32x32x16_f16(u1.h, u1.h, C0, 0, 0, 0);
                    C0 = __builtin_amdgcn_mfma_f32_32x32x16_f16(u2.h, u2.h, C0, 0, 0, 0);
                } else {
                    C1 = __builtin_amdgcn_mfma_f32_32x32x16_f16(u1.h, u1.h, C1, 0, 0, 0);
                    C1 = __builtin_amdgcn_mfma_f32_32x32x16_f16(u2.h, u2.h, C1, 0, 0, 0);
                }
            }

            // epilogue: C IS the correlation; pack f16 pair, upper-tri only
            #pragma unroll
            for (int r = 0; r < 16; ++r) {
                const int il = (r & 3) + 8 * (r >> 2);     // compile-time
                const int i  = il + 4 * hi;                // C row
                if (j > i) {
                    const int p = i * (63 - i) / 2 + (j - i - 1);
                    R.ot[p * OTS + ((pr + p) & 7)] = pkrtz(C0[r], C1[r]);
                }
            }
        }
    }
    __syncthreads();

    // ------------- sweep: ot (f16 pairs) -> out[b][p][chunk*14 + 2wp + {0,1}] ------
    float* ob = out + (size_t)b * NPAIR * T_TOT + chunk * WPB;
    for (int k = tid; k < NPAIR * OTS; k += TPB) {
        const int p   = k >> 3;
        const int slt = k & 7;
        const int wpo = (slt - p) & 7;       // un-swizzle
        if (wpo < 7) {
            const half2_t h = __builtin_bit_cast(half2_t, R.ot[k]);
            float2 o;
            o.x = (float)h.x;
            o.y = (float)h.y;
            *(float2*)&ob[(size_t)p * T_TOT + 2 * wpo] = o;   // 8B aligned
        }
    }
}

extern "C" void kernel_launch(void* const* d_in, const int* in_sizes, int n_in,
                              void* d_out, int out_size, void* d_ws, size_t ws_size,
                              hipStream_t stream) {
    (void)in_sizes; (void)n_in; (void)out_size; (void)d_ws; (void)ws_size;
    const float* x = (const float*)d_in[0];
    float* out     = (float*)d_out;
    const int nblocks = 8 * 32 * NCH;        // 7424
    hipLaunchKernelGGL(tscorr_kernel, dim3(nblocks), dim3(TPB), 0, stream, x, out);
}